// Round 13
// baseline (196.642 us; speedup 1.0000x reference)
//
#include <hip/hip_runtime.h>
#include <hip/hip_bf16.h>

#define NB 8
#define C1 512
#define C2 256
#define HWSZ 4096
#define BN_EPS 1e-5f
#define P2 264   // As2 pitch in ushorts

typedef __hip_bfloat16 bf16;
typedef __hip_bfloat162 bf162;
typedef __attribute__((ext_vector_type(8))) short short8v;
typedef __attribute__((ext_vector_type(4))) float f32x4;

static __device__ inline float b2f(bf16 h) { return __bfloat162float(h); }

static __device__ inline float us2f(unsigned short u) {
  union { unsigned u32; float f; } c; c.u32 = ((unsigned)u) << 16; return c.f;
}

static __device__ inline unsigned short f2bf(float f) {
  union { bf16 h; unsigned short u; } c;
  c.h = __float2bfloat16(f);
  return c.u;
}

static __device__ inline unsigned pack2(float a, float b) {
  union { unsigned u; bf162 h; } pk;
  pk.h = __float22bfloat162_rn(make_float2(a, b));
  return pk.u;
}

static __device__ inline uint2 pack4(float a, float b, float c, float d) {
  union { uint2 u; bf162 h[2]; } pk;
  pk.h[0] = __float22bfloat162_rn(make_float2(a, b));
  pk.h[1] = __float22bfloat162_rn(make_float2(c, d));
  return pk.u;
}

#define SBARQ() asm volatile("s_waitcnt lgkmcnt(0)\n\ts_barrier" ::: "memory")
#define SBAR()  asm volatile("s_barrier" ::: "memory")
#define LGKM0() asm volatile("s_waitcnt lgkmcnt(0)" ::: "memory")

// ---------------------------------------------------------------------------
// K0: swizzle weights into MFMA B-fragment order (bf16).  (unchanged)
// ---------------------------------------------------------------------------
__global__ __launch_bounds__(256) void k0_swizzle(
    const float* __restrict__ wch, const float* __restrict__ wcc1,
    unsigned short* __restrict__ wchB, unsigned short* __restrict__ wcc1B) {
  const int t = blockIdx.x * 256 + threadIdx.x;   // 0 .. 262143
  const int which = t >> 17;
  const int r = t & 131071;
  const int i = r & 7;
  const int lane = (r >> 3) & 63;
  const int ntile = (r >> 9) & 15;
  const int kstep = r >> 13;                      // 0..15
  const int ci = kstep * 32 + (lane >> 4) * 8 + i;
  const int co = ntile * 16 + (lane & 15);
  const float* s = which ? wcc1 : wch;
  unsigned short* d = which ? wcc1B : wchB;
  d[r] = f2bf(s[co * 512 + ci]);
}

// ---------------------------------------------------------------------------
// K12 v5 (byte-identical to round 12)
// ---------------------------------------------------------------------------
__global__ __launch_bounds__(512) void k12_fused(
    const float* __restrict__ x1, const float* __restrict__ x2,
    const unsigned short* __restrict__ wchB, const unsigned short* __restrict__ wcc1B,
    const float* __restrict__ bch,
    const float* __restrict__ gamma, const float* __restrict__ beta,
    const float* __restrict__ mean, const float* __restrict__ var,
    unsigned short* __restrict__ x1c_nhwc, unsigned short* __restrict__ x2_nhwc,
    bf16* __restrict__ xbn) {
  __shared__ unsigned short As[64 * 40];     // staging tile [m][k], pitch 40
  __shared__ unsigned short As2[64 * P2];    // phase A output = phase B A-operand
  const int tid = threadIdx.x;
  const int lane = tid & 63;
  const int wv = tid >> 6;          // 0..7
  const int lrow = lane & 15;
  const int lgrp = lane >> 4;

  const int m0g = blockIdx.x * 64;  // global flat (n*4096 + hw)
  const int n = m0g >> 12;
  const int hw0 = m0g & 4095;
  const int h = hw0 >> 6;

  f32x4 acc[4][2];
#pragma unroll
  for (int mt = 0; mt < 4; ++mt)
#pragma unroll
    for (int nt = 0; nt < 2; ++nt) acc[mt][nt] = (f32x4){0.f, 0.f, 0.f, 0.f};

  // ================= phase A: maxpool + conv1x1(w_change) =================
  const int pmi = tid & 31;
  const int ms = pmi * 2;           // 0..62
  const int ch0 = (tid >> 5) * 2;   // 0..30

  const float* x1p = x1 + (size_t)n * C1 * 16384 + (size_t)(2 * h) * 128 + 2 * ms;

  float4 t0, b0, t1, b1;
#define LOADA(K0_) do { \
    const float* p_ = x1p + (size_t)((K0_) + ch0) * 16384; \
    t0 = *(const float4*)p_;            b0 = *(const float4*)(p_ + 128); \
    t1 = *(const float4*)(p_ + 16384);  b1 = *(const float4*)(p_ + 16384 + 128); \
  } while (0)
#define POOLA(U0_, U1_) do { \
    U0_ = pack2(fmaxf(fmaxf(t0.x, t0.y), fmaxf(b0.x, b0.y)), \
                fmaxf(fmaxf(t1.x, t1.y), fmaxf(b1.x, b1.y))); \
    U1_ = pack2(fmaxf(fmaxf(t0.z, t0.w), fmaxf(b0.z, b0.w)), \
                fmaxf(fmaxf(t1.z, t1.w), fmaxf(b1.z, b1.w))); \
  } while (0)

  unsigned uA0, uA1;
  LOADA(0);
  POOLA(uA0, uA1);
  LOADA(32);               // ks=1 in flight

  for (int ks = 0; ks < 16; ++ks) {
    SBARQ();
    *(unsigned*)&As[ms * 40 + ch0] = uA0;
    *(unsigned*)&As[(ms + 1) * 40 + ch0] = uA1;
    LGKM0();
    SBAR();

    unsigned uN0, uN1;
    if (ks < 15) {
      POOLA(uN0, uN1);
      if (ks < 14) LOADA((ks + 2) * 32);
    }

    short8v a[4];
#pragma unroll
    for (int mt = 0; mt < 4; ++mt)
      a[mt] = *(const short8v*)&As[(mt * 16 + lrow) * 40 + lgrp * 8];
#pragma unroll
    for (int nt = 0; nt < 2; ++nt) {
      const int ntile = wv * 2 + nt;
      const short8v b = *(const short8v*)&wchB[(size_t)((ks * 16 + ntile) * 64 + lane) * 8];
#pragma unroll
      for (int mt = 0; mt < 4; ++mt)
        acc[mt][nt] = __builtin_amdgcn_mfma_f32_16x16x32_bf16(a[mt], b, acc[mt][nt], 0, 0, 0);
    }
    if (ks < 15) { uA0 = uN0; uA1 = uN1; }
  }

  // ---- prefetch x2 for phase B (channels 0..63)
  const int chB = tid >> 4;         // 0..31
  const int mqB = (tid & 15) * 4;   // 0..60
  float4 cf0 = *(const float4*)&x2[((size_t)(n * C2 + chB)) * HWSZ + hw0 + mqB];
  float4 cf1 = *(const float4*)&x2[((size_t)(n * C2 + 32 + chB)) * HWSZ + hw0 + mqB];

  // ---- epilogue A: +bias -> bf16 into As2 only
#pragma unroll
  for (int nt = 0; nt < 2; ++nt) {
    const int co = (wv * 2 + nt) * 16 + lrow;
    const float bias = bch[co];
#pragma unroll
    for (int mt = 0; mt < 4; ++mt) {
      const f32x4 v = acc[mt][nt];
      const uint2 pk = pack4(v.x + bias, v.y + bias, v.z + bias, v.w + bias);
      const int mb = mt * 16 + lgrp * 4;
      As2[(mb + 0) * P2 + co] = (unsigned short)(pk.x & 0xffffu);
      As2[(mb + 1) * P2 + co] = (unsigned short)(pk.x >> 16);
      As2[(mb + 2) * P2 + co] = (unsigned short)(pk.y & 0xffffu);
      As2[(mb + 3) * P2 + co] = (unsigned short)(pk.y >> 16);
      acc[mt][nt] = (f32x4){0.f, 0.f, 0.f, 0.f};
    }
  }
  LGKM0();
  SBAR();   // As2 complete

  // ---- NHWC x1c emission (coalesced from As2)
  {
    const int mm = tid >> 3;
    const int cg = (tid & 7) * 32;
    const size_t ob = ((size_t)(m0g + mm)) * 256 + cg;
#pragma unroll
    for (int k = 0; k < 4; ++k) {
      const uint4 v = *(const uint4*)&As2[mm * P2 + cg + k * 8];
      *(uint4*)&x1c_nhwc[ob + k * 8] = v;
    }
  }

  // ================= phase B: concat + conv1x1(w_cc1) + BN + ReLU ==========
#pragma unroll
  for (int ks = 0; ks < 8; ++ks) {
    short8v a[4];
#pragma unroll
    for (int mt = 0; mt < 4; ++mt)
      a[mt] = *(const short8v*)&As2[(mt * 16 + lrow) * P2 + ks * 32 + lgrp * 8];
#pragma unroll
    for (int nt = 0; nt < 2; ++nt) {
      const int ntile = wv * 2 + nt;
      const short8v b = *(const short8v*)&wcc1B[(size_t)((ks * 16 + ntile) * 64 + lane) * 8];
#pragma unroll
      for (int mt = 0; mt < 4; ++mt)
        acc[mt][nt] = __builtin_amdgcn_mfma_f32_16x16x32_bf16(a[mt], b, acc[mt][nt], 0, 0, 0);
    }
  }

  for (int ks = 8; ks < 16; ++ks) {
    const unsigned p0 = pack2(cf0.x, cf0.y);
    const unsigned p1 = pack2(cf0.z, cf0.w);
    cf0 = cf1;
    if (ks < 14) {
      cf1 = *(const float4*)&x2[((size_t)(n * C2 + (ks - 6) * 32 + chB)) * HWSZ + hw0 + mqB];
    }
    SBARQ();
    As[(mqB + 0) * 40 + chB] = (unsigned short)(p0 & 0xffffu);
    As[(mqB + 1) * 40 + chB] = (unsigned short)(p0 >> 16);
    As[(mqB + 2) * 40 + chB] = (unsigned short)(p1 & 0xffffu);
    As[(mqB + 3) * 40 + chB] = (unsigned short)(p1 >> 16);
    LGKM0();
    SBAR();

    // NHWC x2 emission
    {
      const int m = tid >> 3;
      const int c4 = (tid & 7) * 4;
      const uint2 v = *(const uint2*)&As[m * 40 + c4];
      *(uint2*)&x2_nhwc[((size_t)(m0g + m)) * 256 + (ks - 8) * 32 + c4] = v;
    }

    short8v a[4];
#pragma unroll
    for (int mt = 0; mt < 4; ++mt)
      a[mt] = *(const short8v*)&As[(mt * 16 + lrow) * 40 + lgrp * 8];
#pragma unroll
    for (int nt = 0; nt < 2; ++nt) {
      const int ntile = wv * 2 + nt;
      const short8v b = *(const short8v*)&wcc1B[(size_t)((ks * 16 + ntile) * 64 + lane) * 8];
#pragma unroll
      for (int mt = 0; mt < 4; ++mt)
        acc[mt][nt] = __builtin_amdgcn_mfma_f32_16x16x32_bf16(a[mt], b, acc[mt][nt], 0, 0, 0);
    }
  }

  // ---- epilogue B: BN + ReLU -> bf16 xbn (NCHW)
#pragma unroll
  for (int nt = 0; nt < 2; ++nt) {
    const int co = (wv * 2 + nt) * 16 + lrow;
    const float sc = gamma[co] * rsqrtf(var[co] + BN_EPS);
    const float sh = beta[co] - mean[co] * sc;
#pragma unroll
    for (int mt = 0; mt < 4; ++mt) {
      const f32x4 vv = acc[mt][nt];
      *(uint2*)&xbn[((size_t)(n * C2 + co)) * HWSZ + hw0 + mt * 16 + lgrp * 4] =
          pack4(fmaxf(vv.x * sc + sh, 0.f), fmaxf(vv.y * sc + sh, 0.f),
                fmaxf(vv.z * sc + sh, 0.f), fmaxf(vv.w * sc + sh, 0.f));
    }
  }
#undef LOADA
#undef POOLA
}

// ---------------------------------------------------------------------------
// K34 v2 (byte-identical to round 12)
// ---------------------------------------------------------------------------
__global__ __launch_bounds__(1024) void k34_conv_sample(
    const bf16* __restrict__ xbn, const float* __restrict__ wcc2,
    const unsigned short* __restrict__ x1c_nhwc,
    const unsigned short* __restrict__ x2_nhwc,
    float* __restrict__ out) {
  __shared__ float wsm[9216];          // [ci][dy][dx][f]
  __shared__ float part[16][4][64];
  __shared__ float flr[4][64];
  const int tid = threadIdx.x;
  const int n = blockIdx.x >> 6;
  const int h = blockIdx.x & 63;
  const int wl = tid & 63;
  const int q = tid >> 6;

  for (int idx = tid; idx < 9216; idx += 1024) {
    const int f = idx / 2304;
    const int r = idx % 2304;
    const int ci = r / 9;
    const int t = r % 9;
    wsm[ci * 36 + (t / 3) * 12 + (t % 3) * 4 + f] = wcc2[idx];
  }
  __syncthreads();

  float acc[4] = {0.f, 0.f, 0.f, 0.f};
  {
    const bf16* base = xbn + ((size_t)(n * C2 + q * 16)) * HWSZ;
    const float* wq = wsm + (q * 16) * 36;
    for (int cc = 0; cc < 16; ++cc) {
      const bf16* src = base + (size_t)cc * HWSZ;
      const float* wc = wq + cc * 36;
#pragma unroll
      for (int dy = 0; dy < 3; ++dy) {
        const int y = h + dy - 1;
        if ((unsigned)y >= 64u) continue;
        const float v = b2f(src[y * 64 + wl]);
        float vm = __shfl_up(v, 1);
        float vp = __shfl_down(v, 1);
        if (wl == 0) vm = 0.f;
        if (wl == 63) vp = 0.f;
        const float4 wa = *(const float4*)&wc[dy * 12 + 0];
        const float4 wb = *(const float4*)&wc[dy * 12 + 4];
        const float4 wd = *(const float4*)&wc[dy * 12 + 8];
        acc[0] = fmaf(vm, wa.x, fmaf(v, wb.x, fmaf(vp, wd.x, acc[0])));
        acc[1] = fmaf(vm, wa.y, fmaf(v, wb.y, fmaf(vp, wd.y, acc[1])));
        acc[2] = fmaf(vm, wa.z, fmaf(v, wb.z, fmaf(vp, wd.z, acc[2])));
        acc[3] = fmaf(vm, wa.w, fmaf(v, wb.w, fmaf(vp, wd.w, acc[3])));
      }
    }
  }
  part[q][0][wl] = acc[0];
  part[q][1][wl] = acc[1];
  part[q][2][wl] = acc[2];
  part[q][3][wl] = acc[3];
  __syncthreads();
  if (tid < 256) {
    const int f = tid >> 6;
    const int ww = tid & 63;
    float s = 0.f;
#pragma unroll
    for (int qq = 0; qq < 16; ++qq) s += part[qq][f][ww];
    flr[f][ww] = s;
  }
  __syncthreads();

  const float fx1 = flr[0][wl];
  const float fy1 = flr[1][wl];
  const float fx2 = flr[2][wl];
  const float fy2 = flr[3][wl];

  int oA1, oB1, oC1, oD1; float wa1, wb1, wc1, wd1;
  {
    const float ix = (float)wl + fx1, iy = (float)h + fy1;
    const float x0f = floorf(ix), y0f = floorf(iy);
    const float fx = ix - x0f, fy = iy - y0f;
    const int x0 = (int)x0f, y0 = (int)y0f, x1i = x0 + 1, y1i = y0 + 1;
    const float vx0 = (x0 >= 0 && x0 < 64) ? 1.f : 0.f;
    const float vx1 = (x1i >= 0 && x1i < 64) ? 1.f : 0.f;
    const float vy0 = (y0 >= 0 && y0 < 64) ? 1.f : 0.f;
    const float vy1 = (y1i >= 0 && y1i < 64) ? 1.f : 0.f;
    const int cx0 = min(max(x0, 0), 63), cx1 = min(max(x1i, 0), 63);
    const int cy0 = min(max(y0, 0), 63), cy1 = min(max(y1i, 0), 63);
    oA1 = cy0 * 64 + cx0; oB1 = cy0 * 64 + cx1;
    oC1 = cy1 * 64 + cx0; oD1 = cy1 * 64 + cx1;
    wa1 = (1.f - fx) * (1.f - fy) * vx0 * vy0;
    wb1 = fx * (1.f - fy) * vx1 * vy0;
    wc1 = (1.f - fx) * fy * vx0 * vy1;
    wd1 = fx * fy * vx1 * vy1;
  }
  int oA2, oB2, oC2, oD2; float wa2, wb2, wc2, wd2;
  {
    const float ix = (float)wl + fx2, iy = (float)h + fy2;
    const float x0f = floorf(ix), y0f = floorf(iy);
    const float fx = ix - x0f, fy = iy - y0f;
    const int x0 = (int)x0f, y0 = (int)y0f, x1i = x0 + 1, y1i = y0 + 1;
    const float vx0 = (x0 >= 0 && x0 < 64) ? 1.f : 0.f;
    const float vx1 = (x1i >= 0 && x1i < 64) ? 1.f : 0.f;
    const float vy0 = (y0 >= 0 && y0 < 64) ? 1.f : 0.f;
    const float vy1 = (y1i >= 0 && y1i < 64) ? 1.f : 0.f;
    const int cx0 = min(max(x0, 0), 63), cx1 = min(max(x1i, 0), 63);
    const int cy0 = min(max(y0, 0), 63), cy1 = min(max(y1i, 0), 63);
    oA2 = cy0 * 64 + cx0; oB2 = cy0 * 64 + cx1;
    oC2 = cy1 * 64 + cx0; oD2 = cy1 * 64 + cx1;
    wa2 = (1.f - fx) * (1.f - fy) * vx0 * vy0;
    wb2 = fx * (1.f - fy) * vx1 * vy0;
    wc2 = (1.f - fx) * fy * vx0 * vy1;
    wd2 = fx * fy * vx1 * vy1;
  }

  float u[16];
#pragma unroll
  for (int i = 0; i < 16; ++i) u[i] = 0.f;

  const unsigned short* p1 = x1c_nhwc + ((size_t)n * HWSZ) * 256 + q * 16;
  const unsigned short* p2 = x2_nhwc + ((size_t)n * HWSZ) * 256 + q * 16;

#define TAP(PB_, OFF_, WT_) do { \
    const unsigned short* tp_ = (PB_) + (size_t)(OFF_) * 256; \
    const uint4 v0_ = *(const uint4*)tp_; \
    const uint4 v1_ = *(const uint4*)(tp_ + 8); \
    const unsigned va_[8] = {v0_.x, v0_.y, v0_.z, v0_.w, v1_.x, v1_.y, v1_.z, v1_.w}; \
    _Pragma("unroll") \
    for (int k_ = 0; k_ < 8; ++k_) { \
      u[2 * k_ + 0] = fmaf((WT_), us2f((unsigned short)(va_[k_] & 0xffffu)), u[2 * k_ + 0]); \
      u[2 * k_ + 1] = fmaf((WT_), us2f((unsigned short)(va_[k_] >> 16)),    u[2 * k_ + 1]); \
    } \
  } while (0)

  TAP(p1, oA1, wa1); TAP(p1, oB1, wb1); TAP(p1, oC1, wc1); TAP(p1, oD1, wd1);
  TAP(p2, oA2, wa2); TAP(p2, oB2, wb2); TAP(p2, oC2, wc2); TAP(p2, oD2, wd2);
#undef TAP

  const size_t ob = ((size_t)(n * C2 + q * 16)) * HWSZ + h * 64 + wl;
#pragma unroll
  for (int i = 0; i < 16; ++i) out[ob + (size_t)i * HWSZ] = u[i];
}

// ---------------------------------------------------------------------------
extern "C" void kernel_launch(void* const* d_in, const int* in_sizes, int n_in,
                              void* d_out, int out_size, void* d_ws, size_t ws_size,
                              hipStream_t stream) {
  const float* x1      = (const float*)d_in[0];
  const float* x2      = (const float*)d_in[1];
  const float* w_change= (const float*)d_in[2];
  const float* b_change= (const float*)d_in[3];
  const float* w_cc1   = (const float*)d_in[4];
  const float* bn_gamma= (const float*)d_in[5];
  const float* bn_beta = (const float*)d_in[6];
  const float* bn_mean = (const float*)d_in[7];
  const float* bn_var  = (const float*)d_in[8];
  const float* w_cc2   = (const float*)d_in[9];
  float* out = (float*)d_out;

  unsigned short* x1c_nhwc = (unsigned short*)d_ws;
  bf16*           xbn      = (bf16*)((char*)d_ws + (16u << 20));
  unsigned short* x2_nhwc  = (unsigned short*)((char*)d_ws + (32u << 20));
  unsigned short* wchB     = (unsigned short*)((char*)d_ws + (48u << 20));
  unsigned short* wcc1B    = (unsigned short*)((char*)d_ws + (48u << 20) + (256u << 10));

  k0_swizzle<<<1024, 256, 0, stream>>>(w_change, w_cc1, wchB, wcc1B);
  k12_fused<<<512, 512, 0, stream>>>(x1, x2, wchB, wcc1B, b_change,
                                     bn_gamma, bn_beta, bn_mean, bn_var,
                                     x1c_nhwc, x2_nhwc, xbn);
  // ---- ATTRIBUTION PROBE: K34 launched twice (idempotent). ----
  // K34_warm = dur - 142.6.  Decision tree:
  //   dur ~205+  -> K34 ≈ 65µs, structural pathology; bisect conv vs sample next
  //   dur ~165-175 -> K34 ≈ 25-30µs; residual ~40µs is fixed overhead/gaps ->
  //                   reduce launch count / investigate harness floor next
  k34_conv_sample<<<512, 1024, 0, stream>>>(xbn, w_cc2, x1c_nhwc, x2_nhwc, out);
  k34_conv_sample<<<512, 1024, 0, stream>>>(xbn, w_cc2, x1c_nhwc, x2_nhwc, out);
}

// Round 14
// 139.504 us; speedup vs baseline: 1.4096x; 1.4096x over previous
//
#include <hip/hip_runtime.h>
#include <hip/hip_bf16.h>

#define NB 8
#define C1 512
#define C2 256
#define HWSZ 4096
#define BN_EPS 1e-5f
#define P2 264   // As2 pitch in ushorts

typedef __hip_bfloat16 bf16;
typedef __hip_bfloat162 bf162;
typedef __attribute__((ext_vector_type(8))) short short8v;
typedef __attribute__((ext_vector_type(4))) float f32x4;

static __device__ inline float b2f(bf16 h) { return __bfloat162float(h); }

static __device__ inline float us2f(unsigned short u) {
  union { unsigned u32; float f; } c; c.u32 = ((unsigned)u) << 16; return c.f;
}

static __device__ inline unsigned short f2bf(float f) {
  union { bf16 h; unsigned short u; } c;
  c.h = __float2bfloat16(f);
  return c.u;
}

static __device__ inline unsigned pack2(float a, float b) {
  union { unsigned u; bf162 h; } pk;
  pk.h = __float22bfloat162_rn(make_float2(a, b));
  return pk.u;
}

static __device__ inline uint2 pack4(float a, float b, float c, float d) {
  union { uint2 u; bf162 h[2]; } pk;
  pk.h[0] = __float22bfloat162_rn(make_float2(a, b));
  pk.h[1] = __float22bfloat162_rn(make_float2(c, d));
  return pk.u;
}

#define SBARQ() asm volatile("s_waitcnt lgkmcnt(0)\n\ts_barrier" ::: "memory")
#define SBAR()  asm volatile("s_barrier" ::: "memory")
#define LGKM0() asm volatile("s_waitcnt lgkmcnt(0)" ::: "memory")

// ---------------------------------------------------------------------------
// K0: weight prep — wch/wcc1 -> MFMA B-fragment order (bf16); wcc2 ->
// [ci][dy][dx][f] fp32 reorder for K34.
// ---------------------------------------------------------------------------
__global__ __launch_bounds__(256) void k0_swizzle(
    const float* __restrict__ wch, const float* __restrict__ wcc1,
    const float* __restrict__ wcc2,
    unsigned short* __restrict__ wchB, unsigned short* __restrict__ wcc1B,
    float* __restrict__ wr) {
  const int t = blockIdx.x * 256 + threadIdx.x;   // 0 .. 271359
  if (t < 262144) {
    const int which = t >> 17;
    const int r = t & 131071;
    const int i = r & 7;
    const int lane = (r >> 3) & 63;
    const int ntile = (r >> 9) & 15;
    const int kstep = r >> 13;                      // 0..15
    const int ci = kstep * 32 + (lane >> 4) * 8 + i;
    const int co = ntile * 16 + (lane & 15);
    const float* s = which ? wcc1 : wch;
    unsigned short* d = which ? wcc1B : wchB;
    d[r] = f2bf(s[co * 512 + ci]);
  } else if (t < 262144 + 9216) {
    const int r = t - 262144;          // = f*2304 + ci*9 + tt
    const int f = r / 2304;
    const int rr = r % 2304;
    const int ci = rr / 9;
    const int tt = rr % 9;
    wr[ci * 36 + (tt / 3) * 12 + (tt % 3) * 4 + f] = wcc2[r];
  }
}

// ---------------------------------------------------------------------------
// K12 v5 (byte-identical to round 12)
// ---------------------------------------------------------------------------
__global__ __launch_bounds__(512) void k12_fused(
    const float* __restrict__ x1, const float* __restrict__ x2,
    const unsigned short* __restrict__ wchB, const unsigned short* __restrict__ wcc1B,
    const float* __restrict__ bch,
    const float* __restrict__ gamma, const float* __restrict__ beta,
    const float* __restrict__ mean, const float* __restrict__ var,
    unsigned short* __restrict__ x1c_nhwc, unsigned short* __restrict__ x2_nhwc,
    bf16* __restrict__ xbn) {
  __shared__ unsigned short As[64 * 40];
  __shared__ unsigned short As2[64 * P2];
  const int tid = threadIdx.x;
  const int lane = tid & 63;
  const int wv = tid >> 6;
  const int lrow = lane & 15;
  const int lgrp = lane >> 4;

  const int m0g = blockIdx.x * 64;
  const int n = m0g >> 12;
  const int hw0 = m0g & 4095;
  const int h = hw0 >> 6;

  f32x4 acc[4][2];
#pragma unroll
  for (int mt = 0; mt < 4; ++mt)
#pragma unroll
    for (int nt = 0; nt < 2; ++nt) acc[mt][nt] = (f32x4){0.f, 0.f, 0.f, 0.f};

  const int pmi = tid & 31;
  const int ms = pmi * 2;
  const int ch0 = (tid >> 5) * 2;

  const float* x1p = x1 + (size_t)n * C1 * 16384 + (size_t)(2 * h) * 128 + 2 * ms;

  float4 t0, b0, t1, b1;
#define LOADA(K0_) do { \
    const float* p_ = x1p + (size_t)((K0_) + ch0) * 16384; \
    t0 = *(const float4*)p_;            b0 = *(const float4*)(p_ + 128); \
    t1 = *(const float4*)(p_ + 16384);  b1 = *(const float4*)(p_ + 16384 + 128); \
  } while (0)
#define POOLA(U0_, U1_) do { \
    U0_ = pack2(fmaxf(fmaxf(t0.x, t0.y), fmaxf(b0.x, b0.y)), \
                fmaxf(fmaxf(t1.x, t1.y), fmaxf(b1.x, b1.y))); \
    U1_ = pack2(fmaxf(fmaxf(t0.z, t0.w), fmaxf(b0.z, b0.w)), \
                fmaxf(fmaxf(t1.z, t1.w), fmaxf(b1.z, b1.w))); \
  } while (0)

  unsigned uA0, uA1;
  LOADA(0);
  POOLA(uA0, uA1);
  LOADA(32);

  for (int ks = 0; ks < 16; ++ks) {
    SBARQ();
    *(unsigned*)&As[ms * 40 + ch0] = uA0;
    *(unsigned*)&As[(ms + 1) * 40 + ch0] = uA1;
    LGKM0();
    SBAR();

    unsigned uN0, uN1;
    if (ks < 15) {
      POOLA(uN0, uN1);
      if (ks < 14) LOADA((ks + 2) * 32);
    }

    short8v a[4];
#pragma unroll
    for (int mt = 0; mt < 4; ++mt)
      a[mt] = *(const short8v*)&As[(mt * 16 + lrow) * 40 + lgrp * 8];
#pragma unroll
    for (int nt = 0; nt < 2; ++nt) {
      const int ntile = wv * 2 + nt;
      const short8v b = *(const short8v*)&wchB[(size_t)((ks * 16 + ntile) * 64 + lane) * 8];
#pragma unroll
      for (int mt = 0; mt < 4; ++mt)
        acc[mt][nt] = __builtin_amdgcn_mfma_f32_16x16x32_bf16(a[mt], b, acc[mt][nt], 0, 0, 0);
    }
    if (ks < 15) { uA0 = uN0; uA1 = uN1; }
  }

  const int chB = tid >> 4;
  const int mqB = (tid & 15) * 4;
  float4 cf0 = *(const float4*)&x2[((size_t)(n * C2 + chB)) * HWSZ + hw0 + mqB];
  float4 cf1 = *(const float4*)&x2[((size_t)(n * C2 + 32 + chB)) * HWSZ + hw0 + mqB];

#pragma unroll
  for (int nt = 0; nt < 2; ++nt) {
    const int co = (wv * 2 + nt) * 16 + lrow;
    const float bias = bch[co];
#pragma unroll
    for (int mt = 0; mt < 4; ++mt) {
      const f32x4 v = acc[mt][nt];
      const uint2 pk = pack4(v.x + bias, v.y + bias, v.z + bias, v.w + bias);
      const int mb = mt * 16 + lgrp * 4;
      As2[(mb + 0) * P2 + co] = (unsigned short)(pk.x & 0xffffu);
      As2[(mb + 1) * P2 + co] = (unsigned short)(pk.x >> 16);
      As2[(mb + 2) * P2 + co] = (unsigned short)(pk.y & 0xffffu);
      As2[(mb + 3) * P2 + co] = (unsigned short)(pk.y >> 16);
      acc[mt][nt] = (f32x4){0.f, 0.f, 0.f, 0.f};
    }
  }
  LGKM0();
  SBAR();

  {
    const int mm = tid >> 3;
    const int cg = (tid & 7) * 32;
    const size_t ob = ((size_t)(m0g + mm)) * 256 + cg;
#pragma unroll
    for (int k = 0; k < 4; ++k) {
      const uint4 v = *(const uint4*)&As2[mm * P2 + cg + k * 8];
      *(uint4*)&x1c_nhwc[ob + k * 8] = v;
    }
  }

#pragma unroll
  for (int ks = 0; ks < 8; ++ks) {
    short8v a[4];
#pragma unroll
    for (int mt = 0; mt < 4; ++mt)
      a[mt] = *(const short8v*)&As2[(mt * 16 + lrow) * P2 + ks * 32 + lgrp * 8];
#pragma unroll
    for (int nt = 0; nt < 2; ++nt) {
      const int ntile = wv * 2 + nt;
      const short8v b = *(const short8v*)&wcc1B[(size_t)((ks * 16 + ntile) * 64 + lane) * 8];
#pragma unroll
      for (int mt = 0; mt < 4; ++mt)
        acc[mt][nt] = __builtin_amdgcn_mfma_f32_16x16x32_bf16(a[mt], b, acc[mt][nt], 0, 0, 0);
    }
  }

  for (int ks = 8; ks < 16; ++ks) {
    const unsigned p0 = pack2(cf0.x, cf0.y);
    const unsigned p1 = pack2(cf0.z, cf0.w);
    cf0 = cf1;
    if (ks < 14) {
      cf1 = *(const float4*)&x2[((size_t)(n * C2 + (ks - 6) * 32 + chB)) * HWSZ + hw0 + mqB];
    }
    SBARQ();
    As[(mqB + 0) * 40 + chB] = (unsigned short)(p0 & 0xffffu);
    As[(mqB + 1) * 40 + chB] = (unsigned short)(p0 >> 16);
    As[(mqB + 2) * 40 + chB] = (unsigned short)(p1 & 0xffffu);
    As[(mqB + 3) * 40 + chB] = (unsigned short)(p1 >> 16);
    LGKM0();
    SBAR();

    {
      const int m = tid >> 3;
      const int c4 = (tid & 7) * 4;
      const uint2 v = *(const uint2*)&As[m * 40 + c4];
      *(uint2*)&x2_nhwc[((size_t)(m0g + m)) * 256 + (ks - 8) * 32 + c4] = v;
    }

    short8v a[4];
#pragma unroll
    for (int mt = 0; mt < 4; ++mt)
      a[mt] = *(const short8v*)&As[(mt * 16 + lrow) * 40 + lgrp * 8];
#pragma unroll
    for (int nt = 0; nt < 2; ++nt) {
      const int ntile = wv * 2 + nt;
      const short8v b = *(const short8v*)&wcc1B[(size_t)((ks * 16 + ntile) * 64 + lane) * 8];
#pragma unroll
      for (int mt = 0; mt < 4; ++mt)
        acc[mt][nt] = __builtin_amdgcn_mfma_f32_16x16x32_bf16(a[mt], b, acc[mt][nt], 0, 0, 0);
    }
  }

#pragma unroll
  for (int nt = 0; nt < 2; ++nt) {
    const int co = (wv * 2 + nt) * 16 + lrow;
    const float sc = gamma[co] * rsqrtf(var[co] + BN_EPS);
    const float sh = beta[co] - mean[co] * sc;
#pragma unroll
    for (int mt = 0; mt < 4; ++mt) {
      const f32x4 vv = acc[mt][nt];
      *(uint2*)&xbn[((size_t)(n * C2 + co)) * HWSZ + hw0 + mt * 16 + lgrp * 4] =
          pack4(fmaxf(vv.x * sc + sh, 0.f), fmaxf(vv.y * sc + sh, 0.f),
                fmaxf(vv.z * sc + sh, 0.f), fmaxf(vv.w * sc + sh, 0.f));
    }
  }
#undef LOADA
#undef POOLA
}

// ---------------------------------------------------------------------------
// K34 v3: conv3x3 (as before, pre-reordered weights) -> flow in LDS ->
// sampler with lanes=channels (wave-contiguous 512B tap rows) -> LDS
// transpose -> coalesced NCHW fp32 stores.
// ---------------------------------------------------------------------------
__global__ __launch_bounds__(1024) void k34_conv_sample(
    const bf16* __restrict__ xbn, const float* __restrict__ wr,
    const unsigned short* __restrict__ x1c_nhwc,
    const unsigned short* __restrict__ x2_nhwc,
    float* __restrict__ out) {
  __shared__ union {
    struct { float wsm[9216]; float part[16][4][64]; } c;  // conv: 52 KB
    float outT[256][65];                                   // sample: 65 KB
  } sh;
  __shared__ float flr[4][64];
  __shared__ int   toff[8][64];
  __shared__ float twt[8][64];

  const int tid = threadIdx.x;
  const int n = blockIdx.x >> 6;
  const int h = blockIdx.x & 63;
  const int wl = tid & 63;
  const int q = tid >> 6;

  // ---- load pre-reordered conv weights (linear, coalesced)
  for (int idx = tid; idx < 9216; idx += 1024) sh.c.wsm[idx] = wr[idx];
  __syncthreads();

  // ---- phase 1: conv3x3, q-group handles 16 channels
  float acc[4] = {0.f, 0.f, 0.f, 0.f};
  {
    const bf16* base = xbn + ((size_t)(n * C2 + q * 16)) * HWSZ;
    const float* wq = sh.c.wsm + (q * 16) * 36;
    for (int cc = 0; cc < 16; ++cc) {
      const bf16* src = base + (size_t)cc * HWSZ;
      const float* wc = wq + cc * 36;
#pragma unroll
      for (int dy = 0; dy < 3; ++dy) {
        const int y = h + dy - 1;
        if ((unsigned)y >= 64u) continue;
        const float v = b2f(src[y * 64 + wl]);
        float vm = __shfl_up(v, 1);
        float vp = __shfl_down(v, 1);
        if (wl == 0) vm = 0.f;
        if (wl == 63) vp = 0.f;
        const float4 wa = *(const float4*)&wc[dy * 12 + 0];
        const float4 wb = *(const float4*)&wc[dy * 12 + 4];
        const float4 wd = *(const float4*)&wc[dy * 12 + 8];
        acc[0] = fmaf(vm, wa.x, fmaf(v, wb.x, fmaf(vp, wd.x, acc[0])));
        acc[1] = fmaf(vm, wa.y, fmaf(v, wb.y, fmaf(vp, wd.y, acc[1])));
        acc[2] = fmaf(vm, wa.z, fmaf(v, wb.z, fmaf(vp, wd.z, acc[2])));
        acc[3] = fmaf(vm, wa.w, fmaf(v, wb.w, fmaf(vp, wd.w, acc[3])));
      }
    }
  }
  sh.c.part[q][0][wl] = acc[0];
  sh.c.part[q][1][wl] = acc[1];
  sh.c.part[q][2][wl] = acc[2];
  sh.c.part[q][3][wl] = acc[3];
  __syncthreads();
  if (tid < 256) {
    const int f = tid >> 6;
    const int ww = tid & 63;
    float s = 0.f;
#pragma unroll
    for (int qq = 0; qq < 16; ++qq) s += sh.c.part[qq][f][ww];
    flr[f][ww] = s;
  }
  __syncthreads();   // flr visible

  // ---- taps for each position (tid<64), both samples
  if (tid < 64) {
    const float fxv[2] = {flr[0][tid], flr[2][tid]};
    const float fyv[2] = {flr[1][tid], flr[3][tid]};
#pragma unroll
    for (int s = 0; s < 2; ++s) {
      const float ix = (float)tid + fxv[s], iy = (float)h + fyv[s];
      const float x0f = floorf(ix), y0f = floorf(iy);
      const float fx = ix - x0f, fy = iy - y0f;
      const int x0 = (int)x0f, y0 = (int)y0f, x1i = x0 + 1, y1i = y0 + 1;
      const float vx0 = (x0 >= 0 && x0 < 64) ? 1.f : 0.f;
      const float vx1 = (x1i >= 0 && x1i < 64) ? 1.f : 0.f;
      const float vy0 = (y0 >= 0 && y0 < 64) ? 1.f : 0.f;
      const float vy1 = (y1i >= 0 && y1i < 64) ? 1.f : 0.f;
      const int cx0 = min(max(x0, 0), 63), cx1 = min(max(x1i, 0), 63);
      const int cy0 = min(max(y0, 0), 63), cy1 = min(max(y1i, 0), 63);
      toff[s * 4 + 0][tid] = cy0 * 64 + cx0;
      toff[s * 4 + 1][tid] = cy0 * 64 + cx1;
      toff[s * 4 + 2][tid] = cy1 * 64 + cx0;
      toff[s * 4 + 3][tid] = cy1 * 64 + cx1;
      twt[s * 4 + 0][tid] = (1.f - fx) * (1.f - fy) * vx0 * vy0;
      twt[s * 4 + 1][tid] = fx * (1.f - fy) * vx1 * vy0;
      twt[s * 4 + 2][tid] = (1.f - fx) * fy * vx0 * vy1;
      twt[s * 4 + 3][tid] = fx * fy * vx1 * vy1;
    }
  }
  __syncthreads();   // taps visible; conv LDS (wsm/part) now dead -> outT safe

  // ---- phase 2: sampling. lanes = channels (4 per lane), wave = position.
  {
    const unsigned short* pb1 = x1c_nhwc + (size_t)n * HWSZ * 256 + wl * 4;
    const unsigned short* pb2 = x2_nhwc + (size_t)n * HWSZ * 256 + wl * 4;
#pragma unroll
    for (int pp = 0; pp < 4; ++pp) {
      const int p = q * 4 + pp;
      float u0 = 0.f, u1 = 0.f, u2 = 0.f, u3 = 0.f;
#pragma unroll
      for (int t = 0; t < 8; ++t) {
        const int off = toff[t][p];     // wave-uniform -> LDS broadcast
        const float wt = twt[t][p];
        const unsigned short* rp = (t < 4 ? pb1 : pb2) + (size_t)off * 256;
        const uint2 v = *(const uint2*)rp;   // 8B/lane, 512B/wave contiguous
        u0 = fmaf(wt, us2f((unsigned short)(v.x & 0xffffu)), u0);
        u1 = fmaf(wt, us2f((unsigned short)(v.x >> 16)), u1);
        u2 = fmaf(wt, us2f((unsigned short)(v.y & 0xffffu)), u2);
        u3 = fmaf(wt, us2f((unsigned short)(v.y >> 16)), u3);
      }
      sh.outT[wl * 4 + 0][p] = u0;
      sh.outT[wl * 4 + 1][p] = u1;
      sh.outT[wl * 4 + 2][p] = u2;
      sh.outT[wl * 4 + 3][p] = u3;
    }
  }
  __syncthreads();

  // ---- coalesced NCHW stores: thread (cg = 16ch group, p = lane)
  {
    const int p = tid & 63;
    const int cg = (tid >> 6) * 16;
    const size_t ob = ((size_t)(n * C2 + cg)) * HWSZ + h * 64 + p;
#pragma unroll
    for (int j = 0; j < 16; ++j) {
      out[ob + (size_t)j * HWSZ] = sh.outT[cg + j][p];
    }
  }
}

// ---------------------------------------------------------------------------
extern "C" void kernel_launch(void* const* d_in, const int* in_sizes, int n_in,
                              void* d_out, int out_size, void* d_ws, size_t ws_size,
                              hipStream_t stream) {
  const float* x1      = (const float*)d_in[0];
  const float* x2      = (const float*)d_in[1];
  const float* w_change= (const float*)d_in[2];
  const float* b_change= (const float*)d_in[3];
  const float* w_cc1   = (const float*)d_in[4];
  const float* bn_gamma= (const float*)d_in[5];
  const float* bn_beta = (const float*)d_in[6];
  const float* bn_mean = (const float*)d_in[7];
  const float* bn_var  = (const float*)d_in[8];
  const float* w_cc2   = (const float*)d_in[9];
  float* out = (float*)d_out;

  unsigned short* x1c_nhwc = (unsigned short*)d_ws;
  bf16*           xbn      = (bf16*)((char*)d_ws + (16u << 20));
  unsigned short* x2_nhwc  = (unsigned short*)((char*)d_ws + (32u << 20));
  unsigned short* wchB     = (unsigned short*)((char*)d_ws + (48u << 20));
  unsigned short* wcc1B    = (unsigned short*)((char*)d_ws + (48u << 20) + (256u << 10));
  float*          wr       = (float*)((char*)d_ws + (48u << 20) + (512u << 10));

  k0_swizzle<<<1060, 256, 0, stream>>>(w_change, w_cc1, w_cc2, wchB, wcc1B, wr);
  k12_fused<<<512, 512, 0, stream>>>(x1, x2, wchB, wcc1B, b_change,
                                     bn_gamma, bn_beta, bn_mean, bn_var,
                                     x1c_nhwc, x2_nhwc, xbn);
  k34_conv_sample<<<512, 1024, 0, stream>>>(xbn, wr, x1c_nhwc, x2_nhwc, out);
}